// Round 7
// baseline (853.111 us; speedup 1.0000x reference)
//
#include <hip/hip_runtime.h>
#include <stdint.h>

typedef unsigned short us16;
typedef unsigned short us8  __attribute__((ext_vector_type(8)));
typedef unsigned short us4v __attribute__((ext_vector_type(4)));
typedef __bf16         bf16x8 __attribute__((ext_vector_type(8)));
typedef float          f32x4  __attribute__((ext_vector_type(4)));

__device__ __forceinline__ us16 f2bf(float f) {
    union { float f; unsigned int u; } c; c.f = f;
    unsigned int u = (c.u + 0x7fffu + ((c.u >> 16) & 1u)) >> 16;
    return (us16)u;
}

// async global->LDS, 16 B per lane; LDS dest = wave-uniform base + lane*16
__device__ __forceinline__ void async16(const us16* g, us16* l) {
    __builtin_amdgcn_global_load_lds(
        (const __attribute__((address_space(1))) unsigned int*)g,
        (__attribute__((address_space(3))) unsigned int*)l,
        16, 0, 0);
}

// ---------------------------------------------------------------------------
// device-scope grid barrier (monotone counter; all 1024 blocks co-resident
// by construction: grid=1024, __launch_bounds__(256,4) => 4 blocks/CU,
// LDS 4x32KB=128<=160KB). bar zeroed by host-side memset each launch.
// ---------------------------------------------------------------------------
__device__ __forceinline__ void grid_barrier(unsigned* bar, int phase) {
    __syncthreads();
    if (threadIdx.x == 0) {
        __threadfence();                       // release prior writes, device scope
        atomicAdd(bar, 1u);
        const unsigned target = 1024u * (unsigned)(phase + 1);
        while (__hip_atomic_load(bar, __ATOMIC_ACQUIRE,
                                 __HIP_MEMORY_SCOPE_AGENT) < target)
            __builtin_amdgcn_s_sleep(2);
    }
    __syncthreads();
}

// ---------------------------------------------------------------------------
// GEMM core (R4/R6-proven: BK=64, single-buffered, XOR-swizzle, 0 conflicts)
//  C[n][m] = sum_k A[m][k]*B[n][k], ldC = M.  128x128 tile, 4 waves 2x2,
//  4x4 mfma 16x16x32 bf16.
// EPI: 0 = bf16 + bias[m] (Q/K)   1 = bf16 + bias[n] (V->VT)
//      2 = bf16 exp(acc/32) + atomicAdd row sums into L[n] (scores)
//      3 = f32 acc * (1/L[n]) (out)
// ---------------------------------------------------------------------------
template <int EPI>
__device__ __forceinline__ void gemm_core(
        const us16* __restrict__ A, const us16* __restrict__ B,
        void* __restrict__ C, const float* __restrict__ bias,
        float* __restrict__ L,
        int M, int K, int x, int y, us16* lsA, us16* lsB) {
    const int m0 = x * 128, n0 = y * 128;
    const int tid = threadIdx.x;
    const int lane = tid & 63, wid = tid >> 6;
    const int l15 = lane & 15, quad = lane >> 4;
    const int wm = (wid & 1) * 64, wn = (wid >> 1) * 64;

    f32x4 acc[4][4] = {};

    const int srow = wid * 32 + (lane >> 3);
    const int sc8 = (lane & 7) ^ ((lane >> 3) & 7);
    const us16* Ap = A + (size_t)(m0 + srow) * K + sc8 * 8;
    const us16* Bp = B + (size_t)(n0 + srow) * K + sc8 * 8;
    us16* ldsAw = &lsA[(wid * 32) * 64];
    us16* ldsBw = &lsB[(wid * 32) * 64];

    for (int kb = 0; kb < K; kb += 64) {
        __syncthreads();
#pragma unroll
        for (int c = 0; c < 4; c++) {
            async16(Ap + kb + (size_t)(c * 8) * K, ldsAw + c * 8 * 64);
            async16(Bp + kb + (size_t)(c * 8) * K, ldsBw + c * 8 * 64);
        }
        __syncthreads();
#pragma unroll
        for (int ks = 0; ks < 2; ks++) {
            bf16x8 af[4], bfr[4];
#pragma unroll
            for (int i = 0; i < 4; i++) {
                const int ra = wm + i * 16 + l15;
                const int rb = wn + i * 16 + l15;
                const int pa = ((ks * 4 + quad) ^ (ra & 7)) * 8;
                const int pb = ((ks * 4 + quad) ^ (rb & 7)) * 8;
                af[i]  = *(const bf16x8*)(&lsA[ra * 64 + pa]);
                bfr[i] = *(const bf16x8*)(&lsB[rb * 64 + pb]);
            }
#pragma unroll
            for (int i = 0; i < 4; i++)
#pragma unroll
                for (int j = 0; j < 4; j++)
                    acc[i][j] = __builtin_amdgcn_mfma_f32_16x16x32_bf16(af[i], bfr[j], acc[i][j], 0, 0, 0);
        }
    }

    if (EPI == 2) {
        const float scale = 0.03125f;
        float rs[4] = {0.f, 0.f, 0.f, 0.f};
#pragma unroll
        for (int i = 0; i < 4; i++) {
            const int mb = m0 + wm + i * 16 + quad * 4;
#pragma unroll
            for (int j = 0; j < 4; j++) {
                const int n = n0 + wn + j * 16 + l15;
                f32x4 v = acc[i][j];
                const float e0 = __expf(v[0] * scale), e1 = __expf(v[1] * scale);
                const float e2 = __expf(v[2] * scale), e3 = __expf(v[3] * scale);
                rs[j] += (e0 + e1) + (e2 + e3);
                us4v st = { f2bf(e0), f2bf(e1), f2bf(e2), f2bf(e3) };
                *(us4v*)((us16*)C + (size_t)n * M + mb) = st;
            }
        }
#pragma unroll
        for (int j = 0; j < 4; j++) {
            rs[j] += __shfl_xor(rs[j], 16, 64);
            rs[j] += __shfl_xor(rs[j], 32, 64);
        }
        if (quad == 0) {
#pragma unroll
            for (int j = 0; j < 4; j++)
                atomicAdd(&L[n0 + wn + j * 16 + l15], rs[j]);
        }
        return;
    }

#pragma unroll
    for (int i = 0; i < 4; i++) {
        const int mb = m0 + wm + i * 16 + quad * 4;
        float b0 = 0.f, b1 = 0.f, b2 = 0.f, b3 = 0.f;
        if (EPI == 0) {
            float4 bv4 = *(const float4*)(bias + mb);
            b0 = bv4.x; b1 = bv4.y; b2 = bv4.z; b3 = bv4.w;
        }
#pragma unroll
        for (int j = 0; j < 4; j++) {
            const int n = n0 + wn + j * 16 + l15;
            f32x4 v = acc[i][j];
            if (EPI == 3) {
                const float inv = 1.0f / L[n];
                float4 st;
                st.x = v[0] * inv; st.y = v[1] * inv;
                st.z = v[2] * inv; st.w = v[3] * inv;
                *(float4*)((float*)C + (size_t)n * M + mb) = st;
            } else {
                const float bn = (EPI == 1) ? bias[n] : 0.0f;
                us4v st = { f2bf(v[0] + b0 + bn), f2bf(v[1] + b1 + bn),
                            f2bf(v[2] + b2 + bn), f2bf(v[3] + b3 + bn) };
                *(us4v*)((us16*)C + (size_t)n * M + mb) = st;
            }
        }
    }
}

// strip swizzle: lin in [0, gx*gy), strips of 4 m-panels.
__device__ __forceinline__ void strip_xy(int lin, int gy, int& x, int& y) {
    const int within = lin & (4 * gy - 1);   // gy is 8 or 16 (pow2)
    x = (lin / (4 * gy)) * 4 + (within & 3);
    y = within >> 2;
}

// ---------------------------------------------------------------------------
// mega: persistent kernel, grid 1024 x 256, 4 phases with grid barriers.
// ---------------------------------------------------------------------------
__global__ __launch_bounds__(256, 4)
void mega(const float* __restrict__ x,
          const float* __restrict__ Wq, const float* __restrict__ bq,
          const float* __restrict__ Wk, const float* __restrict__ bk,
          const float* __restrict__ Wv, const float* __restrict__ bv,
          float* __restrict__ out, char* __restrict__ ws) {
    __shared__ us16 lsA[8192];
    __shared__ us16 lsB[8192];

    const size_t SZ = 16777216;   // B*S*D bf16 bytes
    us16* Qb = (us16*)(ws);
    us16* Kb = (us16*)(ws + SZ);
    us16* VT = (us16*)(ws + 2 * SZ);            // [B][D][S]
    us16* XT = (us16*)(ws + 3 * SZ);            // [B][S][D]
    us16* Wb = (us16*)(ws + 4 * SZ);            // [3][1024][1024]
    us16* Sb = (us16*)(ws + 3 * SZ);            // P~ [B][S][S], aliases dead XT/Wb
    float* Lb = (float*)(ws + 5 * SZ);          // L [B][S] (memset 0 by host)
    unsigned* bar = (unsigned*)(ws + 5 * SZ + 32768);  // barrier counter (memset 0)

    const long long sXT = 2097152;   // S*D
    const long long sSS = 4194304;   // S*S
    const int bid = blockIdx.x;
    const int t = threadIdx.x;

    // ---- phase 0: prep (5120 units: 2048 transpose-x + 3072 convert-W) ----
    for (int u = bid; u < 5120; u += 1024) {
        if (u < 2048) {
            us16* tile = lsA;                    // 64*65 = 4160 <= 8192
            const int s0 = (u & 31) * 64, d0 = ((u >> 5) & 15) * 64, b = u >> 9;
            const float* xp = x + ((size_t)b * 1024 + d0) * 2048 + s0;
            const int r = t >> 4, c4 = t & 15;
#pragma unroll
            for (int i = 0; i < 4; i++) {
                float4 v = *(const float4*)(xp + (size_t)(r + 16 * i) * 2048 + c4 * 4);
                const int d = r + 16 * i;
                tile[(c4 * 4 + 0) * 65 + d] = f2bf(v.x);
                tile[(c4 * 4 + 1) * 65 + d] = f2bf(v.y);
                tile[(c4 * 4 + 2) * 65 + d] = f2bf(v.z);
                tile[(c4 * 4 + 3) * 65 + d] = f2bf(v.w);
            }
            __syncthreads();
            us16* op = XT + ((size_t)b * 2048 + s0) * 1024 + d0;
#pragma unroll
            for (int i = 0; i < 2; i++) {
                const int uu = t + 256 * i;
                const int s = uu >> 3, c8 = uu & 7;
                us8 o;
#pragma unroll
                for (int j = 0; j < 8; j++) o[j] = tile[s * 65 + c8 * 8 + j];
                *(us8*)(op + (size_t)s * 1024 + c8 * 8) = o;
            }
        } else {
            const int cid = u - 2048;            // 0..3071
            const int mb = cid >> 10;
            const float* src = (mb == 0) ? Wq : (mb == 1) ? Wk : Wv;
            const size_t off = ((size_t)(cid & 1023) * 256 + t) * 4;
            float4 v = *(const float4*)(src + off);
            us4v o = { f2bf(v.x), f2bf(v.y), f2bf(v.z), f2bf(v.w) };
            *(us4v*)(Wb + (size_t)mb * 1048576 + off) = o;
        }
        __syncthreads();                         // protect lsA reuse across units
    }
    grid_barrier(bar, 0);

    // ---- phase 1: qkv (1536 units) ----
    for (int u = bid; u < 1536; u += 1024) {
        if (u < 1024) {
            const int z = u >> 7, zz = z & 3;
            const bool isK = z >= 4;
            int xx, yy; strip_xy(u & 127, 16, xx, yy);
            const us16* A = Wb + (isK ? 1048576 : 0);
            const us16* B = XT + (size_t)zz * sXT;
            us16* C = (isK ? Kb : Qb) + (size_t)zz * sXT;
            gemm_core<0>(A, B, (void*)C, isK ? bk : bq, nullptr, 1024, 1024, xx, yy, lsA, lsB);
        } else {
            const int u2 = u - 1024;
            const int z = u2 >> 7;
            int xx, yy; strip_xy(u2 & 127, 8, xx, yy);
            gemm_core<1>(XT + (size_t)z * sXT, Wb + 2097152,
                         (void*)(VT + (size_t)z * sXT), bv, nullptr,
                         2048, 1024, xx, yy, lsA, lsB);
        }
    }
    grid_barrier(bar, 1);

    // ---- phase 2: scores (1024 units) ----
    {
        const int z = bid >> 8;
        int xx, yy; strip_xy(bid & 255, 16, xx, yy);
        gemm_core<2>(Kb + (size_t)z * sXT, Qb + (size_t)z * sXT,
                     (void*)(Sb + (size_t)z * sSS), nullptr, Lb + z * 2048,
                     2048, 1024, xx, yy, lsA, lsB);
    }
    grid_barrier(bar, 2);

    // ---- phase 3: out (512 units) ----
    if (bid < 512) {
        const int z = bid >> 7;
        int xx, yy; strip_xy(bid & 127, 16, xx, yy);
        gemm_core<3>(VT + (size_t)z * sXT, Sb + (size_t)z * sSS,
                     (void*)(out + (size_t)z * sXT), nullptr, Lb + z * 2048,
                     1024, 2048, xx, yy, lsA, lsB);
    }
}

// ---------------------------------------------------------------------------
extern "C" void kernel_launch(void* const* d_in, const int* in_sizes, int n_in,
                              void* d_out, int out_size, void* d_ws, size_t ws_size,
                              hipStream_t stream) {
    const float* x  = (const float*)d_in[0];
    const float* Wq = (const float*)d_in[1];
    const float* bq = (const float*)d_in[2];
    const float* Wk = (const float*)d_in[3];
    const float* bk = (const float*)d_in[4];
    const float* Wv = (const float*)d_in[5];
    const float* bv = (const float*)d_in[6];
    float* out = (float*)d_out;
    char* ws = (char*)d_ws;

    const size_t SZ = 16777216;
    // zero L (32 KB) + barrier counter (4 B) in one memset
    hipMemsetAsync(ws + 5 * SZ, 0, 32768 + 64, stream);
    mega<<<dim3(1024, 1, 1), dim3(256, 1, 1), 0, stream>>>(
        x, Wq, bq, Wk, bk, Wv, bv, out, ws);
}

// Round 8
// 681.862 us; speedup vs baseline: 1.2511x; 1.2511x over previous
//
#include <hip/hip_runtime.h>
#include <stdint.h>

typedef unsigned short us16;
typedef unsigned short us8  __attribute__((ext_vector_type(8)));
typedef unsigned short us4v __attribute__((ext_vector_type(4)));
typedef __bf16         bf16x8 __attribute__((ext_vector_type(8)));
typedef float          f32x4  __attribute__((ext_vector_type(4)));

__device__ __forceinline__ us16 f2bf(float f) {
    union { float f; unsigned int u; } c; c.f = f;
    unsigned int u = (c.u + 0x7fffu + ((c.u >> 16) & 1u)) >> 16;
    return (us16)u;
}

// async global->LDS, 16 B per lane; LDS dest = wave-uniform base + lane*16
__device__ __forceinline__ void async16(const us16* g, us16* l) {
    __builtin_amdgcn_global_load_lds(
        (const __attribute__((address_space(1))) unsigned int*)g,
        (__attribute__((address_space(3))) unsigned int*)l,
        16, 0, 0);
}

// ---------------------------------------------------------------------------
// device-scope grid barrier. All 1024 blocks co-resident (grid=1024,
// __launch_bounds__(256,4) => 4 blocks/CU, LDS 4x32KB=128<=160KB).
// R8 fix: spin with RELAXED agent-scope loads (no per-poll cache
// invalidate — R7's ACQUIRE poll emitted buffer_inv every iteration,
// thrashing every XCD's L2 for the whole phase-skew window), then ONE
// acquire fence after the loop.
// ---------------------------------------------------------------------------
__device__ __forceinline__ void grid_barrier(unsigned* bar, int phase) {
    __syncthreads();
    if (threadIdx.x == 0) {
        __threadfence();   // release: make this block's writes device-visible
        __hip_atomic_fetch_add(bar, 1u, __ATOMIC_RELAXED,
                               __HIP_MEMORY_SCOPE_AGENT);
        const unsigned target = 1024u * (unsigned)(phase + 1);
        while (__hip_atomic_load(bar, __ATOMIC_RELAXED,
                                 __HIP_MEMORY_SCOPE_AGENT) < target)
            __builtin_amdgcn_s_sleep(8);
        __threadfence();   // acquire: see other blocks' writes (single inv)
    }
    __syncthreads();
}

// ---------------------------------------------------------------------------
// GEMM core (R4/R6-proven: BK=64, single-buffered, XOR-swizzle, 0 conflicts)
//  C[n][m] = sum_k A[m][k]*B[n][k], ldC = M.  128x128 tile, 4 waves 2x2,
//  4x4 mfma 16x16x32 bf16.
// EPI: 0 = bf16 + bias[m] (Q/K)   1 = bf16 + bias[n] (V->VT)
//      2 = bf16 exp(acc/32) + atomicAdd row sums into L[n] (scores)
//      3 = f32 acc * (1/L[n]) (out)
// ---------------------------------------------------------------------------
template <int EPI>
__device__ __forceinline__ void gemm_core(
        const us16* __restrict__ A, const us16* __restrict__ B,
        void* __restrict__ C, const float* __restrict__ bias,
        float* __restrict__ L,
        int M, int K, int x, int y, us16* lsA, us16* lsB) {
    const int m0 = x * 128, n0 = y * 128;
    const int tid = threadIdx.x;
    const int lane = tid & 63, wid = tid >> 6;
    const int l15 = lane & 15, quad = lane >> 4;
    const int wm = (wid & 1) * 64, wn = (wid >> 1) * 64;

    f32x4 acc[4][4] = {};

    const int srow = wid * 32 + (lane >> 3);
    const int sc8 = (lane & 7) ^ ((lane >> 3) & 7);
    const us16* Ap = A + (size_t)(m0 + srow) * K + sc8 * 8;
    const us16* Bp = B + (size_t)(n0 + srow) * K + sc8 * 8;
    us16* ldsAw = &lsA[(wid * 32) * 64];
    us16* ldsBw = &lsB[(wid * 32) * 64];

    for (int kb = 0; kb < K; kb += 64) {
        __syncthreads();
#pragma unroll
        for (int c = 0; c < 4; c++) {
            async16(Ap + kb + (size_t)(c * 8) * K, ldsAw + c * 8 * 64);
            async16(Bp + kb + (size_t)(c * 8) * K, ldsBw + c * 8 * 64);
        }
        __syncthreads();
#pragma unroll
        for (int ks = 0; ks < 2; ks++) {
            bf16x8 af[4], bfr[4];
#pragma unroll
            for (int i = 0; i < 4; i++) {
                const int ra = wm + i * 16 + l15;
                const int rb = wn + i * 16 + l15;
                const int pa = ((ks * 4 + quad) ^ (ra & 7)) * 8;
                const int pb = ((ks * 4 + quad) ^ (rb & 7)) * 8;
                af[i]  = *(const bf16x8*)(&lsA[ra * 64 + pa]);
                bfr[i] = *(const bf16x8*)(&lsB[rb * 64 + pb]);
            }
#pragma unroll
            for (int i = 0; i < 4; i++)
#pragma unroll
                for (int j = 0; j < 4; j++)
                    acc[i][j] = __builtin_amdgcn_mfma_f32_16x16x32_bf16(af[i], bfr[j], acc[i][j], 0, 0, 0);
        }
    }

    if (EPI == 2) {
        const float scale = 0.03125f;
        float rs[4] = {0.f, 0.f, 0.f, 0.f};
#pragma unroll
        for (int i = 0; i < 4; i++) {
            const int mb = m0 + wm + i * 16 + quad * 4;
#pragma unroll
            for (int j = 0; j < 4; j++) {
                const int n = n0 + wn + j * 16 + l15;
                f32x4 v = acc[i][j];
                const float e0 = __expf(v[0] * scale), e1 = __expf(v[1] * scale);
                const float e2 = __expf(v[2] * scale), e3 = __expf(v[3] * scale);
                rs[j] += (e0 + e1) + (e2 + e3);
                us4v st = { f2bf(e0), f2bf(e1), f2bf(e2), f2bf(e3) };
                *(us4v*)((us16*)C + (size_t)n * M + mb) = st;
            }
        }
#pragma unroll
        for (int j = 0; j < 4; j++) {
            rs[j] += __shfl_xor(rs[j], 16, 64);
            rs[j] += __shfl_xor(rs[j], 32, 64);
        }
        if (quad == 0) {
#pragma unroll
            for (int j = 0; j < 4; j++)
                atomicAdd(&L[n0 + wn + j * 16 + l15], rs[j]);
        }
        return;
    }

#pragma unroll
    for (int i = 0; i < 4; i++) {
        const int mb = m0 + wm + i * 16 + quad * 4;
        float b0 = 0.f, b1 = 0.f, b2 = 0.f, b3 = 0.f;
        if (EPI == 0) {
            float4 bv4 = *(const float4*)(bias + mb);
            b0 = bv4.x; b1 = bv4.y; b2 = bv4.z; b3 = bv4.w;
        }
#pragma unroll
        for (int j = 0; j < 4; j++) {
            const int n = n0 + wn + j * 16 + l15;
            f32x4 v = acc[i][j];
            if (EPI == 3) {
                const float inv = 1.0f / L[n];
                float4 st;
                st.x = v[0] * inv; st.y = v[1] * inv;
                st.z = v[2] * inv; st.w = v[3] * inv;
                *(float4*)((float*)C + (size_t)n * M + mb) = st;
            } else {
                const float bn = (EPI == 1) ? bias[n] : 0.0f;
                us4v st = { f2bf(v[0] + b0 + bn), f2bf(v[1] + b1 + bn),
                            f2bf(v[2] + b2 + bn), f2bf(v[3] + b3 + bn) };
                *(us4v*)((us16*)C + (size_t)n * M + mb) = st;
            }
        }
    }
}

// strip swizzle: lin in [0, gx*gy), strips of 4 m-panels.
__device__ __forceinline__ void strip_xy(int lin, int gy, int& x, int& y) {
    const int within = lin & (4 * gy - 1);   // gy is 8 or 16 (pow2)
    x = (lin / (4 * gy)) * 4 + (within & 3);
    y = within >> 2;
}

// ---------------------------------------------------------------------------
// mega: persistent kernel, grid 1024 x 256, 4 phases with grid barriers.
// ---------------------------------------------------------------------------
__global__ __launch_bounds__(256, 4)
void mega(const float* __restrict__ x,
          const float* __restrict__ Wq, const float* __restrict__ bq,
          const float* __restrict__ Wk, const float* __restrict__ bk,
          const float* __restrict__ Wv, const float* __restrict__ bv,
          float* __restrict__ out, char* __restrict__ ws) {
    __shared__ us16 lsA[8192];
    __shared__ us16 lsB[8192];

    const size_t SZ = 16777216;   // B*S*D bf16 bytes
    us16* Qb = (us16*)(ws);
    us16* Kb = (us16*)(ws + SZ);
    us16* VT = (us16*)(ws + 2 * SZ);            // [B][D][S]
    us16* XT = (us16*)(ws + 3 * SZ);            // [B][S][D]
    us16* Wb = (us16*)(ws + 4 * SZ);            // [3][1024][1024]
    us16* Sb = (us16*)(ws + 3 * SZ);            // P~ [B][S][S], aliases dead XT/Wb
    float* Lb = (float*)(ws + 5 * SZ);          // L [B][S] (memset 0 by host)
    unsigned* bar = (unsigned*)(ws + 5 * SZ + 32768);  // barrier counter (memset 0)

    const long long sXT = 2097152;   // S*D
    const long long sSS = 4194304;   // S*S
    const int bid = blockIdx.x;
    const int t = threadIdx.x;

    // ---- phase 0: prep (5120 units: 2048 transpose-x + 3072 convert-W) ----
    for (int u = bid; u < 5120; u += 1024) {
        if (u < 2048) {
            us16* tile = lsA;                    // 64*65 = 4160 <= 8192
            const int s0 = (u & 31) * 64, d0 = ((u >> 5) & 15) * 64, b = u >> 9;
            const float* xp = x + ((size_t)b * 1024 + d0) * 2048 + s0;
            const int r = t >> 4, c4 = t & 15;
#pragma unroll
            for (int i = 0; i < 4; i++) {
                float4 v = *(const float4*)(xp + (size_t)(r + 16 * i) * 2048 + c4 * 4);
                const int d = r + 16 * i;
                tile[(c4 * 4 + 0) * 65 + d] = f2bf(v.x);
                tile[(c4 * 4 + 1) * 65 + d] = f2bf(v.y);
                tile[(c4 * 4 + 2) * 65 + d] = f2bf(v.z);
                tile[(c4 * 4 + 3) * 65 + d] = f2bf(v.w);
            }
            __syncthreads();
            us16* op = XT + ((size_t)b * 2048 + s0) * 1024 + d0;
#pragma unroll
            for (int i = 0; i < 2; i++) {
                const int uu = t + 256 * i;
                const int s = uu >> 3, c8 = uu & 7;
                us8 o;
#pragma unroll
                for (int j = 0; j < 8; j++) o[j] = tile[s * 65 + c8 * 8 + j];
                *(us8*)(op + (size_t)s * 1024 + c8 * 8) = o;
            }
        } else {
            const int cid = u - 2048;            // 0..3071
            const int mb = cid >> 10;
            const float* src = (mb == 0) ? Wq : (mb == 1) ? Wk : Wv;
            const size_t off = ((size_t)(cid & 1023) * 256 + t) * 4;
            float4 v = *(const float4*)(src + off);
            us4v o = { f2bf(v.x), f2bf(v.y), f2bf(v.z), f2bf(v.w) };
            *(us4v*)(Wb + (size_t)mb * 1048576 + off) = o;
        }
        __syncthreads();                         // protect lsA reuse across units
    }
    grid_barrier(bar, 0);

    // ---- phase 1: qkv (1536 units) ----
    for (int u = bid; u < 1536; u += 1024) {
        if (u < 1024) {
            const int z = u >> 7, zz = z & 3;
            const bool isK = z >= 4;
            int xx, yy; strip_xy(u & 127, 16, xx, yy);
            const us16* A = Wb + (isK ? 1048576 : 0);
            const us16* B = XT + (size_t)zz * sXT;
            us16* C = (isK ? Kb : Qb) + (size_t)zz * sXT;
            gemm_core<0>(A, B, (void*)C, isK ? bk : bq, nullptr, 1024, 1024, xx, yy, lsA, lsB);
        } else {
            const int u2 = u - 1024;
            const int z = u2 >> 7;
            int xx, yy; strip_xy(u2 & 127, 8, xx, yy);
            gemm_core<1>(XT + (size_t)z * sXT, Wb + 2097152,
                         (void*)(VT + (size_t)z * sXT), bv, nullptr,
                         2048, 1024, xx, yy, lsA, lsB);
        }
    }
    grid_barrier(bar, 1);

    // ---- phase 2: scores (1024 units) ----
    {
        const int z = bid >> 8;
        int xx, yy; strip_xy(bid & 255, 16, xx, yy);
        gemm_core<2>(Kb + (size_t)z * sXT, Qb + (size_t)z * sXT,
                     (void*)(Sb + (size_t)z * sSS), nullptr, Lb + z * 2048,
                     2048, 1024, xx, yy, lsA, lsB);
    }
    grid_barrier(bar, 2);

    // ---- phase 3: out (512 units) ----
    if (bid < 512) {
        const int z = bid >> 7;
        int xx, yy; strip_xy(bid & 127, 16, xx, yy);
        gemm_core<3>(VT + (size_t)z * sXT, Sb + (size_t)z * sSS,
                     (void*)(out + (size_t)z * sXT), nullptr, Lb + z * 2048,
                     1024, 2048, xx, yy, lsA, lsB);
    }
}

// ---------------------------------------------------------------------------
extern "C" void kernel_launch(void* const* d_in, const int* in_sizes, int n_in,
                              void* d_out, int out_size, void* d_ws, size_t ws_size,
                              hipStream_t stream) {
    const float* x  = (const float*)d_in[0];
    const float* Wq = (const float*)d_in[1];
    const float* bq = (const float*)d_in[2];
    const float* Wk = (const float*)d_in[3];
    const float* bk = (const float*)d_in[4];
    const float* Wv = (const float*)d_in[5];
    const float* bv = (const float*)d_in[6];
    float* out = (float*)d_out;
    char* ws = (char*)d_ws;

    const size_t SZ = 16777216;
    // zero L (32 KB) + barrier counter in one memset
    hipMemsetAsync(ws + 5 * SZ, 0, 32768 + 64, stream);
    mega<<<dim3(1024, 1, 1), dim3(256, 1, 1), 0, stream>>>(
        x, Wq, bq, Wk, bk, Wv, bv, out, ws);
}